// Round 6
// baseline (268.309 us; speedup 1.0000x reference)
//
#include <hip/hip_runtime.h>
#include <math.h>

#define IMG_W 2048
#define IMG_H 2048
#define BATCH 8
#define MAX_PEAKS ((BATCH * IMG_H * IMG_W) / 8)   // 4194304
#define NWORDS (BATCH * IMG_H * IMG_W / 32)       // 1048576
#define NFILL 2048                                // tail-fill blocks

// ---------------------------------------------------------------------------
// Non-temporal access helpers. Theory: the harness's 512 MiB poison fill
// leaves the 256 MiB L3 full of dirty lines; every normal read miss in K1
// then forces a dirty writeback (hidden +1x HBM traffic on the critical
// path), capping effective read BW at ~2.4 TB/s regardless of kernel
// structure (explains 5 consecutive structural nulls). NT loads/stores
// don't allocate -> no eviction -> no writeback tax. All our streams are
// touch-once, so losing cacheability costs nothing.
// ---------------------------------------------------------------------------
typedef float vf4 __attribute__((ext_vector_type(4)));
typedef int vi4 __attribute__((ext_vector_type(4)));
typedef unsigned vu4 __attribute__((ext_vector_type(4)));

__device__ __forceinline__ float4 ntload_f4(const void* p) {
    vf4 v = __builtin_nontemporal_load((const vf4*)p);
    return *(const float4*)&v;
}
__device__ __forceinline__ uint4 ntload_u4(const void* p) {
    vu4 v = __builtin_nontemporal_load((const vu4*)p);
    return *(const uint4*)&v;
}
__device__ __forceinline__ void ntstore_u32(unsigned* p, unsigned v) {
    __builtin_nontemporal_store(v, p);
}
__device__ __forceinline__ void ntstore_i32(int* p, int v) {
    __builtin_nontemporal_store(v, p);
}
__device__ __forceinline__ void ntstore_i4(void* p, int4 v) {
    __builtin_nontemporal_store(*(vi4*)&v, (vi4*)p);
}

// ---------------------------------------------------------------------------
// K1: separable 5x5 NMS, zero per-row cross-lane ops (r4 structure, verified)
// with NON-TEMPORAL streaming loads. Wave = 64 lanes x 4 cols x 16 rows;
// lane loads 3 aligned float4/row (qL,qM,qR share cache lines with
// neighbors); H-ring/m-ring named registers; 8x8 nibble transpose merge.
// mask bit = (s > 0) && (s >= 5x5 window max).
// ---------------------------------------------------------------------------

#define LOAD3(i)                                                              \
  {                                                                           \
    q##i##L = ntload_f4(pL);                                                  \
    q##i##M = ntload_f4(pM);                                                  \
    q##i##R = ntload_f4(pR);                                                  \
    const size_t stepB =                                                      \
        ((unsigned)(xn - 1) < 2047u) ? (size_t)(IMG_W * 4) : (size_t)0;       \
    pL += stepB;                                                              \
    pM += stepB;                                                              \
    pR += stepB;                                                              \
    ++xn;                                                                     \
  }

#define COMP(i, HS, MS)                                                       \
  {                                                                           \
    const float qlz = fixL ? NEG : q##i##L.z;                                 \
    const float qlw = fixL ? NEG : q##i##L.w;                                 \
    const float qrx = fixR ? NEG : q##i##R.x;                                 \
    const float qry = fixR ? NEG : q##i##R.y;                                 \
    const float4 qm = q##i##M;                                                \
    const float ab = fmaxf(qm.x, qm.y);                                       \
    const float cd = fmaxf(qm.z, qm.w);                                       \
    const float bc = fmaxf(qm.y, qm.z);                                       \
    const float abcd = fmaxf(ab, cd);                                         \
    HS.x = fmaxf(fmaxf(qlz, qlw), fmaxf(ab, qm.z));                           \
    HS.y = fmaxf(qlw, abcd);                                                  \
    HS.z = fmaxf(abcd, qrx);                                                  \
    HS.w = fmaxf(fmaxf(bc, qm.w), fmaxf(qrx, qry));                           \
    MS = qm;                                                                  \
  }

#define OUT(MS, pos)                                                          \
  {                                                                           \
    const float vx = fmaxf(fmaxf(fmaxf(H0.x, H1.x), fmaxf(H2.x, H3.x)), H4.x);\
    const float vy = fmaxf(fmaxf(fmaxf(H0.y, H1.y), fmaxf(H2.y, H3.y)), H4.y);\
    const float vz = fmaxf(fmaxf(fmaxf(H0.z, H1.z), fmaxf(H2.z, H3.z)), H4.z);\
    const float vw = fmaxf(fmaxf(fmaxf(H0.w, H1.w), fmaxf(H2.w, H3.w)), H4.w);\
    unsigned nib = 0;                                                         \
    nib |= (MS.x > 0.0f && MS.x >= vx) ? 1u : 0u;                             \
    nib |= (MS.y > 0.0f && MS.y >= vy) ? 2u : 0u;                             \
    nib |= (MS.z > 0.0f && MS.z >= vz) ? 4u : 0u;                             \
    nib |= (MS.w > 0.0f && MS.w >= vw) ? 8u : 0u;                             \
    bacc |= nib << (4 * (pos));                                               \
  }

// 8x8 nibble transpose across each aligned lane-octet, then one coalesced
// 64-lane NT store (verified in r4).
#define MERGE(g)                                                              \
  {                                                                           \
    unsigned x = bacc, y;                                                     \
    y = __shfl_xor(x, 4);                                                     \
    x = (lane & 4) ? ((y >> 16) | (x & 0xFFFF0000u))                          \
                   : ((x & 0x0000FFFFu) | (y << 16));                         \
    y = __shfl_xor(x, 2);                                                     \
    x = (lane & 2) ? (((y >> 8) & 0x00FF00FFu) | (x & 0xFF00FF00u))           \
                   : ((x & 0x00FF00FFu) | ((y << 8) & 0xFF00FF00u));          \
    y = __shfl_xor(x, 1);                                                     \
    x = (lane & 1) ? (((y >> 4) & 0x0F0F0F0Fu) | (x & 0xF0F0F0F0u))           \
                   : ((x & 0x0F0F0F0Fu) | ((y << 4) & 0xF0F0F0F0u));          \
    ntstore_u32(&words[wIdx0 + (g) * 512u], x);                               \
    cnt += __popc(x);                                                         \
    bacc = 0;                                                                 \
  }

__global__ __launch_bounds__(256, 4) void nms_mask(const float* __restrict__ scores,
                                                   unsigned* __restrict__ words,
                                                   unsigned* __restrict__ bsum2) {
    const int t = threadIdx.x;
    const int lane = t & 63;
    const int wv = t >> 6;
    const int b = blockIdx.x;                 // 0..2047
    const int L = (b >> 3) + (b & 7) * 256;   // one image per XCD
    const int img = L >> 8;
    const int rem = L & 255;
    const int strip = rem >> 5;               // 8 strips of 256 cols
    const int chunk = rem & 31;               // 32 chunks of 64 rows
    const int r0 = chunk * 64 + wv * 16;      // 16 rows per wave
    const int c0 = strip * 256;
    const int cl = c0 + lane * 4;
    const size_t imgBase = (size_t)img * ((size_t)IMG_H * IMG_W);
    const float NEG = -INFINITY;

    const bool fixL = (lane == 0) && (strip == 0);
    const bool fixR = (lane == 63) && (strip == 7);

    const int rstart = (r0 - 2) < 0 ? 0 : (r0 - 2);
    const char* rowp = (const char*)(scores + imgBase + (size_t)rstart * IMG_W);
    const char* pL = rowp + 4 * (cl - 4) + (fixL ? 16 : 0);
    const char* pM = rowp + 4 * cl;
    const char* pR = rowp + 4 * (cl + 4) - (fixR ? 16 : 0);
    int xn = r0 - 1;   // virtual-row counter (replicates rows 0/2047)

    float4 q0L, q0M, q0R, q1L, q1M, q1R, q2L, q2M, q2R, q3L, q3M, q3R;
    float4 H0, H1, H2, H3, H4;
    float4 m0, m1, m2;

    unsigned cnt = 0, bacc = 0;
    const unsigned wIdx0 =
        (unsigned)(img * IMG_H + r0 + (lane & 7)) * 64u + strip * 8u + (lane >> 3);
    const int cb0 = (img * IMG_H + r0) >> 4;

    // warmup rows r0-2..r0 -> slots 0..2; steady distance-3 pipeline
    LOAD3(0); LOAD3(1); LOAD3(2);
    LOAD3(3); COMP(0, H0, m0);
    LOAD3(0); COMP(1, H1, m1);
    LOAD3(1); COMP(2, H2, m2);
    LOAD3(2); COMP(3, H3, m0);
    LOAD3(3); COMP(0, H4, m1); OUT(m2, 0);
    LOAD3(0); COMP(1, H0, m2); OUT(m0, 1);
    LOAD3(1); COMP(2, H1, m0); OUT(m1, 2);
    LOAD3(2); COMP(3, H2, m1); OUT(m2, 3);
    LOAD3(3); COMP(0, H3, m2); OUT(m0, 4);
    LOAD3(0); COMP(1, H4, m0); OUT(m1, 5);
    LOAD3(1); COMP(2, H0, m1); OUT(m2, 6);
    LOAD3(2); COMP(3, H1, m2); OUT(m0, 7); MERGE(0);
    LOAD3(3); COMP(0, H2, m0); OUT(m1, 0);
    LOAD3(0); COMP(1, H3, m1); OUT(m2, 1);
    LOAD3(1); COMP(2, H4, m2); OUT(m0, 2);
    LOAD3(2); COMP(3, H0, m0); OUT(m1, 3);
    LOAD3(3); COMP(0, H1, m1); OUT(m2, 4);
              COMP(1, H2, m2); OUT(m0, 5);
              COMP(2, H3, m0); OUT(m1, 6);
              COMP(3, H4, m1); OUT(m2, 7); MERGE(1);

    unsigned s = cnt;
    s += __shfl_xor(s, 1);
    s += __shfl_xor(s, 2);
    s += __shfl_xor(s, 4);
    s += __shfl_xor(s, 8);
    s += __shfl_xor(s, 16);
    s += __shfl_xor(s, 32);
    if (lane == 0) bsum2[cb0 * 8 + strip] = s;
}

// ---------------------------------------------------------------------------
// K2: scan (unchanged, known-good). 8192 slots -> 1024 cb bases + total.
// ---------------------------------------------------------------------------
__global__ __launch_bounds__(256) void nms_scan(const unsigned* __restrict__ bsum2,
                                                unsigned* __restrict__ base) {
    __shared__ unsigned wtot[4];
    const int t = threadIdx.x;
    const int lane = t & 63, wid = t >> 6;
    const uint4* p = (const uint4*)(bsum2 + t * 32);   // 4 cbs x 8 slots
    unsigned c[4];
#pragma unroll
    for (int i = 0; i < 4; ++i) {
        uint4 a = p[2 * i], bq = p[2 * i + 1];
        c[i] = a.x + a.y + a.z + a.w + bq.x + bq.y + bq.z + bq.w;
    }
    unsigned s0 = c[0], s1 = s0 + c[1], s2 = s1 + c[2], ts = s2 + c[3];
    unsigned sc = ts;
#pragma unroll
    for (int d = 1; d < 64; d <<= 1) {
        unsigned o = __shfl_up(sc, d);
        if (lane >= d) sc += o;
    }
    if (lane == 63) wtot[wid] = sc;
    __syncthreads();
    unsigned wpre = 0;
#pragma unroll
    for (int k = 0; k < 4; ++k) wpre += (k < wid) ? wtot[k] : 0u;
    unsigned excl = wpre + sc - ts;
    ((uint4*)base)[t] = make_uint4(excl, excl + s0, excl + s1, excl + s2);
    if (t == 255) base[1024] = wpre + sc;
}

// ---------------------------------------------------------------------------
// K3: ordered compaction + -1 tail fill, all output stores NON-TEMPORAL
// (out is never re-read), words read non-temporal (touch-once).
// ---------------------------------------------------------------------------
__global__ __launch_bounds__(256) void nms_compact(const unsigned* __restrict__ words,
                                                   const unsigned* __restrict__ base,
                                                   int* __restrict__ out) {
    const int t = threadIdx.x;
    const int b = blockIdx.x;
    if (b < 1024) {
        __shared__ unsigned wq[4];
        const int lane = t & 63, wid = t >> 6;
        uint4 q = ntload_u4((const uint4*)(words + b * 1024) + t);
        unsigned wv[4] = {q.x, q.y, q.z, q.w};
        unsigned tsum = __popc(wv[0]) + __popc(wv[1]) + __popc(wv[2]) + __popc(wv[3]);
        unsigned sc = tsum;
#pragma unroll
        for (int d = 1; d < 64; d <<= 1) {
            unsigned o = __shfl_up(sc, d);
            if (lane >= d) sc += o;
        }
        if (lane == 63) wq[wid] = sc;
        __syncthreads();
        unsigned wpre = 0;
#pragma unroll
        for (int k = 0; k < 4; ++k) wpre += (k < wid) ? wq[k] : 0u;
        unsigned off = base[b] + wpre + sc - tsum;

        const unsigned gword0 = (unsigned)b * 1024u + (unsigned)t * 4u;
#pragma unroll
        for (int wi = 0; wi < 4; ++wi) {
            unsigned m = wv[wi];
            unsigned pbase = (gword0 + wi) << 5;
            while (m) {
                int bit = __builtin_ctz(m);
                m &= m - 1;
                unsigned ppix = pbase + (unsigned)bit;
                int hh = (int)((ppix >> 11) & 2047u);
                int ww = (int)(ppix & 2047u);
                if (off < (unsigned)MAX_PEAKS) {
                    ntstore_i32(&out[off], hh);
                    ntstore_i32(&out[MAX_PEAKS + off], ww);
                }
                ++off;
            }
        }
    } else {
        unsigned total = base[1024];
        if (total > (unsigned)MAX_PEAKS) total = MAX_PEAKS;
        unsigned tail = (unsigned)MAX_PEAKS - total;
        unsigned fb = (unsigned)(b - 1024);
        unsigned per = (tail + NFILL - 1) / NFILL;
        unsigned s = total + fb * per;
        unsigned e = s + per;
        if (s > (unsigned)MAX_PEAKS) s = MAX_PEAKS;
        if (e > (unsigned)MAX_PEAKS) e = MAX_PEAKS;
        unsigned a = (s + 3u) & ~3u;
        if (a > e) a = e;
        unsigned e4 = e & ~3u;
        if (e4 < a) e4 = a;
        if ((unsigned)t < a - s) {
            ntstore_i32(&out[s + t], -1);
            ntstore_i32(&out[MAX_PEAKS + s + t], -1);
        }
        const int4 m4 = make_int4(-1, -1, -1, -1);
        for (unsigned k = a / 4 + t; k < e4 / 4; k += 256) {
            ntstore_i4(&((int4*)out)[k], m4);
            ntstore_i4(&((int4*)(out + MAX_PEAKS))[k], m4);
        }
        if ((unsigned)t < e - e4) {
            ntstore_i32(&out[e4 + t], -1);
            ntstore_i32(&out[MAX_PEAKS + e4 + t], -1);
        }
    }
}

extern "C" void kernel_launch(void* const* d_in, const int* in_sizes, int n_in,
                              void* d_out, int out_size, void* d_ws, size_t ws_size,
                              hipStream_t stream) {
    const float* scores = (const float*)d_in[0];
    int* out = (int*)d_out;
    unsigned* words = (unsigned*)d_ws;            // 1,048,576 words (4 MB)
    unsigned* bsum2 = words + NWORDS;             // 8192 per-(16-row,strip) sums
    unsigned* base = bsum2 + 8192;                // 1025 (incl. total)

    nms_mask<<<2048, 256, 0, stream>>>(scores, words, bsum2);
    nms_scan<<<1, 256, 0, stream>>>(bsum2, base);
    nms_compact<<<1024 + NFILL, 256, 0, stream>>>(words, base, out);
}

// Round 7
// 242.909 us; speedup vs baseline: 1.1046x; 1.1046x over previous
//
#include <hip/hip_runtime.h>
#include <math.h>

#define IMG_W 2048
#define IMG_H 2048
#define BATCH 8
#define MAX_PEAKS ((BATCH * IMG_H * IMG_W) / 8)   // 4194304
#define NWORDS (BATCH * IMG_H * IMG_W / 32)       // 1048576
#define NFILL 2048                                // tail-fill blocks

// ---------------------------------------------------------------------------
// PROBE ROUND: r4's verified kernel (best non-spill structure, normal cached
// loads), with nms_mask launched TWICE. The kernel is idempotent (every
// words[]/bsum2[] slot unconditionally overwritten), so correctness is
// unchanged. The second launch reads the 134 MB input L3-warm ->
// dur_us - 216.6 == K1's non-HBM-bound (warm) duration. This disambiguates:
//   World A (K1~60us, stuck at 2.4 TB/s cold AND warm): issue-bound, keep digging.
//   World B (K1~27us): K1 was at BW floor since r0; remainder is harness-fixed.
// ---------------------------------------------------------------------------

#define LOAD3(i)                                                              \
  {                                                                           \
    q##i##L = *(const float4*)pL;                                             \
    q##i##M = *(const float4*)pM;                                             \
    q##i##R = *(const float4*)pR;                                             \
    const size_t stepB =                                                      \
        ((unsigned)(xn - 1) < 2047u) ? (size_t)(IMG_W * 4) : (size_t)0;       \
    pL += stepB;                                                              \
    pM += stepB;                                                              \
    pR += stepB;                                                              \
    ++xn;                                                                     \
  }

#define COMP(i, HS, MS)                                                       \
  {                                                                           \
    const float qlz = fixL ? NEG : q##i##L.z;                                 \
    const float qlw = fixL ? NEG : q##i##L.w;                                 \
    const float qrx = fixR ? NEG : q##i##R.x;                                 \
    const float qry = fixR ? NEG : q##i##R.y;                                 \
    const float4 qm = q##i##M;                                                \
    const float ab = fmaxf(qm.x, qm.y);                                       \
    const float cd = fmaxf(qm.z, qm.w);                                       \
    const float bc = fmaxf(qm.y, qm.z);                                       \
    const float abcd = fmaxf(ab, cd);                                         \
    HS.x = fmaxf(fmaxf(qlz, qlw), fmaxf(ab, qm.z));                           \
    HS.y = fmaxf(qlw, abcd);                                                  \
    HS.z = fmaxf(abcd, qrx);                                                  \
    HS.w = fmaxf(fmaxf(bc, qm.w), fmaxf(qrx, qry));                           \
    MS = qm;                                                                  \
  }

#define OUT(MS, pos)                                                          \
  {                                                                           \
    const float vx = fmaxf(fmaxf(fmaxf(H0.x, H1.x), fmaxf(H2.x, H3.x)), H4.x);\
    const float vy = fmaxf(fmaxf(fmaxf(H0.y, H1.y), fmaxf(H2.y, H3.y)), H4.y);\
    const float vz = fmaxf(fmaxf(fmaxf(H0.z, H1.z), fmaxf(H2.z, H3.z)), H4.z);\
    const float vw = fmaxf(fmaxf(fmaxf(H0.w, H1.w), fmaxf(H2.w, H3.w)), H4.w);\
    unsigned nib = 0;                                                         \
    nib |= (MS.x > 0.0f && MS.x >= vx) ? 1u : 0u;                             \
    nib |= (MS.y > 0.0f && MS.y >= vy) ? 2u : 0u;                             \
    nib |= (MS.z > 0.0f && MS.z >= vz) ? 4u : 0u;                             \
    nib |= (MS.w > 0.0f && MS.w >= vw) ? 8u : 0u;                             \
    bacc |= nib << (4 * (pos));                                               \
  }

#define MERGE(g)                                                              \
  {                                                                           \
    unsigned x = bacc, y;                                                     \
    y = __shfl_xor(x, 4);                                                     \
    x = (lane & 4) ? ((y >> 16) | (x & 0xFFFF0000u))                          \
                   : ((x & 0x0000FFFFu) | (y << 16));                         \
    y = __shfl_xor(x, 2);                                                     \
    x = (lane & 2) ? (((y >> 8) & 0x00FF00FFu) | (x & 0xFF00FF00u))           \
                   : ((x & 0x00FF00FFu) | ((y << 8) & 0xFF00FF00u));          \
    y = __shfl_xor(x, 1);                                                     \
    x = (lane & 1) ? (((y >> 4) & 0x0F0F0F0Fu) | (x & 0xF0F0F0F0u))           \
                   : ((x & 0x0F0F0F0Fu) | ((y << 4) & 0xF0F0F0F0u));          \
    words[wIdx0 + (g) * 512u] = x;                                            \
    cnt += __popc(x);                                                         \
    bacc = 0;                                                                 \
  }

__global__ __launch_bounds__(256, 4) void nms_mask(const float* __restrict__ scores,
                                                   unsigned* __restrict__ words,
                                                   unsigned* __restrict__ bsum2) {
    const int t = threadIdx.x;
    const int lane = t & 63;
    const int wv = t >> 6;
    const int b = blockIdx.x;                 // 0..2047
    const int L = (b >> 3) + (b & 7) * 256;   // one image per XCD
    const int img = L >> 8;
    const int rem = L & 255;
    const int strip = rem >> 5;               // 8 strips of 256 cols
    const int chunk = rem & 31;               // 32 chunks of 64 rows
    const int r0 = chunk * 64 + wv * 16;      // 16 rows per wave
    const int c0 = strip * 256;
    const int cl = c0 + lane * 4;
    const size_t imgBase = (size_t)img * ((size_t)IMG_H * IMG_W);
    const float NEG = -INFINITY;

    const bool fixL = (lane == 0) && (strip == 0);
    const bool fixR = (lane == 63) && (strip == 7);

    const int rstart = (r0 - 2) < 0 ? 0 : (r0 - 2);
    const char* rowp = (const char*)(scores + imgBase + (size_t)rstart * IMG_W);
    const char* pL = rowp + 4 * (cl - 4) + (fixL ? 16 : 0);
    const char* pM = rowp + 4 * cl;
    const char* pR = rowp + 4 * (cl + 4) - (fixR ? 16 : 0);
    int xn = r0 - 1;   // virtual-row counter (replicates rows 0/2047)

    float4 q0L, q0M, q0R, q1L, q1M, q1R, q2L, q2M, q2R, q3L, q3M, q3R;
    float4 H0, H1, H2, H3, H4;
    float4 m0, m1, m2;

    unsigned cnt = 0, bacc = 0;
    const unsigned wIdx0 =
        (unsigned)(img * IMG_H + r0 + (lane & 7)) * 64u + strip * 8u + (lane >> 3);
    const int cb0 = (img * IMG_H + r0) >> 4;

    // warmup rows r0-2..r0 -> slots 0..2; steady distance-3 pipeline
    LOAD3(0); LOAD3(1); LOAD3(2);
    LOAD3(3); COMP(0, H0, m0);
    LOAD3(0); COMP(1, H1, m1);
    LOAD3(1); COMP(2, H2, m2);
    LOAD3(2); COMP(3, H3, m0);
    LOAD3(3); COMP(0, H4, m1); OUT(m2, 0);
    LOAD3(0); COMP(1, H0, m2); OUT(m0, 1);
    LOAD3(1); COMP(2, H1, m0); OUT(m1, 2);
    LOAD3(2); COMP(3, H2, m1); OUT(m2, 3);
    LOAD3(3); COMP(0, H3, m2); OUT(m0, 4);
    LOAD3(0); COMP(1, H4, m0); OUT(m1, 5);
    LOAD3(1); COMP(2, H0, m1); OUT(m2, 6);
    LOAD3(2); COMP(3, H1, m2); OUT(m0, 7); MERGE(0);
    LOAD3(3); COMP(0, H2, m0); OUT(m1, 0);
    LOAD3(0); COMP(1, H3, m1); OUT(m2, 1);
    LOAD3(1); COMP(2, H4, m2); OUT(m0, 2);
    LOAD3(2); COMP(3, H0, m0); OUT(m1, 3);
    LOAD3(3); COMP(0, H1, m1); OUT(m2, 4);
              COMP(1, H2, m2); OUT(m0, 5);
              COMP(2, H3, m0); OUT(m1, 6);
              COMP(3, H4, m1); OUT(m2, 7); MERGE(1);

    unsigned s = cnt;
    s += __shfl_xor(s, 1);
    s += __shfl_xor(s, 2);
    s += __shfl_xor(s, 4);
    s += __shfl_xor(s, 8);
    s += __shfl_xor(s, 16);
    s += __shfl_xor(s, 32);
    if (lane == 0) bsum2[cb0 * 8 + strip] = s;
}

// ---------------------------------------------------------------------------
// K2: scan. 8192 slots -> 1024 cb bases + total. One 256-thread block.
// ---------------------------------------------------------------------------
__global__ __launch_bounds__(256) void nms_scan(const unsigned* __restrict__ bsum2,
                                                unsigned* __restrict__ base) {
    __shared__ unsigned wtot[4];
    const int t = threadIdx.x;
    const int lane = t & 63, wid = t >> 6;
    const uint4* p = (const uint4*)(bsum2 + t * 32);   // 4 cbs x 8 slots
    unsigned c[4];
#pragma unroll
    for (int i = 0; i < 4; ++i) {
        uint4 a = p[2 * i], bq = p[2 * i + 1];
        c[i] = a.x + a.y + a.z + a.w + bq.x + bq.y + bq.z + bq.w;
    }
    unsigned s0 = c[0], s1 = s0 + c[1], s2 = s1 + c[2], ts = s2 + c[3];
    unsigned sc = ts;
#pragma unroll
    for (int d = 1; d < 64; d <<= 1) {
        unsigned o = __shfl_up(sc, d);
        if (lane >= d) sc += o;
    }
    if (lane == 63) wtot[wid] = sc;
    __syncthreads();
    unsigned wpre = 0;
#pragma unroll
    for (int k = 0; k < 4; ++k) wpre += (k < wid) ? wtot[k] : 0u;
    unsigned excl = wpre + sc - ts;
    ((uint4*)base)[t] = make_uint4(excl, excl + s0, excl + s1, excl + s2);
    if (t == 255) base[1024] = wpre + sc;
}

// ---------------------------------------------------------------------------
// K3: ordered compaction (blocks 0..1023) + -1 tail fill (blocks 1024..).
// ---------------------------------------------------------------------------
__global__ __launch_bounds__(256) void nms_compact(const unsigned* __restrict__ words,
                                                   const unsigned* __restrict__ base,
                                                   int* __restrict__ out) {
    const int t = threadIdx.x;
    const int b = blockIdx.x;
    if (b < 1024) {
        __shared__ unsigned wq[4];
        const int lane = t & 63, wid = t >> 6;
        uint4 q = ((const uint4*)(words + b * 1024))[t];
        unsigned wv[4] = {q.x, q.y, q.z, q.w};
        unsigned tsum = __popc(wv[0]) + __popc(wv[1]) + __popc(wv[2]) + __popc(wv[3]);
        unsigned sc = tsum;
#pragma unroll
        for (int d = 1; d < 64; d <<= 1) {
            unsigned o = __shfl_up(sc, d);
            if (lane >= d) sc += o;
        }
        if (lane == 63) wq[wid] = sc;
        __syncthreads();
        unsigned wpre = 0;
#pragma unroll
        for (int k = 0; k < 4; ++k) wpre += (k < wid) ? wq[k] : 0u;
        unsigned off = base[b] + wpre + sc - tsum;

        const unsigned gword0 = (unsigned)b * 1024u + (unsigned)t * 4u;
#pragma unroll
        for (int wi = 0; wi < 4; ++wi) {
            unsigned m = wv[wi];
            unsigned pbase = (gword0 + wi) << 5;
            while (m) {
                int bit = __builtin_ctz(m);
                m &= m - 1;
                unsigned ppix = pbase + (unsigned)bit;
                int hh = (int)((ppix >> 11) & 2047u);
                int ww = (int)(ppix & 2047u);
                if (off < (unsigned)MAX_PEAKS) {
                    out[off] = hh;
                    out[MAX_PEAKS + off] = ww;
                }
                ++off;
            }
        }
    } else {
        unsigned total = base[1024];
        if (total > (unsigned)MAX_PEAKS) total = MAX_PEAKS;
        unsigned tail = (unsigned)MAX_PEAKS - total;
        unsigned fb = (unsigned)(b - 1024);
        unsigned per = (tail + NFILL - 1) / NFILL;
        unsigned s = total + fb * per;
        unsigned e = s + per;
        if (s > (unsigned)MAX_PEAKS) s = MAX_PEAKS;
        if (e > (unsigned)MAX_PEAKS) e = MAX_PEAKS;
        unsigned a = (s + 3u) & ~3u;
        if (a > e) a = e;
        unsigned e4 = e & ~3u;
        if (e4 < a) e4 = a;
        if ((unsigned)t < a - s) {
            out[s + t] = -1;
            out[MAX_PEAKS + s + t] = -1;
        }
        const int4 m4 = make_int4(-1, -1, -1, -1);
        for (unsigned k = a / 4 + t; k < e4 / 4; k += 256) {
            ((int4*)out)[k] = m4;
            ((int4*)(out + MAX_PEAKS))[k] = m4;
        }
        if ((unsigned)t < e - e4) {
            out[e4 + t] = -1;
            out[MAX_PEAKS + e4 + t] = -1;
        }
    }
}

extern "C" void kernel_launch(void* const* d_in, const int* in_sizes, int n_in,
                              void* d_out, int out_size, void* d_ws, size_t ws_size,
                              hipStream_t stream) {
    const float* scores = (const float*)d_in[0];
    int* out = (int*)d_out;
    unsigned* words = (unsigned*)d_ws;            // 1,048,576 words (4 MB)
    unsigned* bsum2 = words + NWORDS;             // 8192 per-(16-row,strip) sums
    unsigned* base = bsum2 + 8192;                // 1025 (incl. total)

    // PROBE: double-launch of the idempotent mask kernel. The second launch
    // reads the input L3-warm; dur_us delta vs r4 (216.6) == warm K1 cost.
    nms_mask<<<2048, 256, 0, stream>>>(scores, words, bsum2);
    nms_mask<<<2048, 256, 0, stream>>>(scores, words, bsum2);
    nms_scan<<<1, 256, 0, stream>>>(bsum2, base);
    nms_compact<<<1024 + NFILL, 256, 0, stream>>>(words, base, out);
}

// Round 8
// 219.935 us; speedup vs baseline: 1.2200x; 1.1045x over previous
//
#include <hip/hip_runtime.h>
#include <math.h>

#define IMG_W 2048
#define IMG_H 2048
#define BATCH 8
#define MAX_PEAKS ((BATCH * IMG_H * IMG_W) / 8)   // 4194304
#define NWORDS (BATCH * IMG_H * IMG_W / 32)       // 1048576
#define NFILL 2048                                // tail-fill blocks

// ---------------------------------------------------------------------------
// K1: FULL-WIDTH-BAND separable 5x5 NMS (DRAM-sequential read pattern).
// r7 probe: K1 cold = 64.7us, warm = 26.3us -> cold is HBM-fetch-bound at
// ~2.2 TB/s. All prior variants (incl. 144KB/CU-in-flight DMA) read ~3000
// concurrent 1KB-granule 8KB-strided streams -> DRAM page/channel thrash.
// New mapping: block = ONE CONTIGUOUS 128KB band (16 rows x full 8KB width),
// 4 waves side-by-side (512 cols each, 8 cols/lane), streamed row-by-row ->
// 1024 sequential streams with ~8KB effective granule (the copy-ubench
// pattern that achieves 6.3 TB/s). Lane reads 64B/row (qL|M0|M1|qR, 2x line
// overlap absorbed by L1/L2). H-max at load (warm probe proved huge issue
// slack); named 5-deep H ring + 3-deep mid ring; per-row 2-shfl merge.
// mask bit = (s > 0) && (s >= 5x5 window max).
// ---------------------------------------------------------------------------

#define LOADH(Ha, Hb, mA, mB)                                                 \
  {                                                                           \
    const float4 qL = *(const float4*)(pB + offL);                            \
    const float4 M0 = *(const float4*)(pB);                                   \
    const float4 M1 = *(const float4*)(pB + 16);                              \
    const float4 qR = *(const float4*)(pB + offR);                            \
    const size_t stepB =                                                      \
        ((unsigned)(xn - 1) < 2047u) ? (size_t)(IMG_W * 4) : (size_t)0;       \
    pB += stepB;                                                              \
    ++xn;                                                                     \
    const float qlz = fixL ? NEG : qL.z;                                      \
    const float qlw = fixL ? NEG : qL.w;                                      \
    const float qrx = fixR ? NEG : qR.x;                                      \
    const float qry = fixR ? NEG : qR.y;                                      \
    const float t01 = fmaxf(M0.x, M0.y);                                      \
    const float t23 = fmaxf(M0.z, M0.w);                                      \
    const float t45 = fmaxf(M1.x, M1.y);                                      \
    const float t67 = fmaxf(M1.z, M1.w);                                      \
    const float t03 = fmaxf(t01, t23);                                        \
    const float t47 = fmaxf(t45, t67);                                        \
    Ha.x = fmaxf(fmaxf(qlz, qlw), fmaxf(t01, M0.z));                          \
    Ha.y = fmaxf(qlw, t03);                                                   \
    Ha.z = fmaxf(t03, M1.x);                                                  \
    Ha.w = fmaxf(fmaxf(M0.y, t23), t45);                                      \
    Hb.x = fmaxf(t23, fmaxf(t45, M1.z));                                      \
    Hb.y = fmaxf(M0.w, t47);                                                  \
    Hb.z = fmaxf(t47, qrx);                                                   \
    Hb.w = fmaxf(fmaxf(M1.y, t67), fmaxf(qrx, qry));                          \
    mA = M0;                                                                  \
    mB = M1;                                                                  \
  }

#define OUT(mA, mB, idx)                                                      \
  {                                                                           \
    const float vax = fmaxf(fmaxf(fmaxf(Ha0.x, Ha1.x), fmaxf(Ha2.x, Ha3.x)), Ha4.x); \
    const float vay = fmaxf(fmaxf(fmaxf(Ha0.y, Ha1.y), fmaxf(Ha2.y, Ha3.y)), Ha4.y); \
    const float vaz = fmaxf(fmaxf(fmaxf(Ha0.z, Ha1.z), fmaxf(Ha2.z, Ha3.z)), Ha4.z); \
    const float vaw = fmaxf(fmaxf(fmaxf(Ha0.w, Ha1.w), fmaxf(Ha2.w, Ha3.w)), Ha4.w); \
    const float vbx = fmaxf(fmaxf(fmaxf(Hb0.x, Hb1.x), fmaxf(Hb2.x, Hb3.x)), Hb4.x); \
    const float vby = fmaxf(fmaxf(fmaxf(Hb0.y, Hb1.y), fmaxf(Hb2.y, Hb3.y)), Hb4.y); \
    const float vbz = fmaxf(fmaxf(fmaxf(Hb0.z, Hb1.z), fmaxf(Hb2.z, Hb3.z)), Hb4.z); \
    const float vbw = fmaxf(fmaxf(fmaxf(Hb0.w, Hb1.w), fmaxf(Hb2.w, Hb3.w)), Hb4.w); \
    unsigned byte = 0;                                                        \
    byte |= (mA.x > 0.0f && mA.x >= vax) ? 0x01u : 0u;                        \
    byte |= (mA.y > 0.0f && mA.y >= vay) ? 0x02u : 0u;                        \
    byte |= (mA.z > 0.0f && mA.z >= vaz) ? 0x04u : 0u;                        \
    byte |= (mA.w > 0.0f && mA.w >= vaw) ? 0x08u : 0u;                        \
    byte |= (mB.x > 0.0f && mB.x >= vbx) ? 0x10u : 0u;                        \
    byte |= (mB.y > 0.0f && mB.y >= vby) ? 0x20u : 0u;                        \
    byte |= (mB.z > 0.0f && mB.z >= vbz) ? 0x40u : 0u;                        \
    byte |= (mB.w > 0.0f && mB.w >= vbw) ? 0x80u : 0u;                        \
    unsigned x = byte << ((lane & 3) * 8);                                    \
    x |= __shfl_xor(x, 1);                                                    \
    x |= __shfl_xor(x, 2);                                                    \
    if ((lane & 3) == 0) {                                                    \
      words[wIdx0 + (idx) * 64u] = x;                                         \
      cnt += __popc(x);                                                       \
    }                                                                         \
  }

__global__ __launch_bounds__(256, 4) void nms_mask(const float* __restrict__ scores,
                                                   unsigned* __restrict__ words,
                                                   unsigned* __restrict__ bsum2) {
    const int t = threadIdx.x;
    const int lane = t & 63;
    const int wv = t >> 6;                    // wave = 512-col panel
    const int b = blockIdx.x;                 // 0..1023
    const int img = b & 7;                    // XCD swizzle: image per XCD
    const int band = b >> 3;                  // 0..127: 16-row band, top->down
    const int r0 = band * 16;
    const int cl = wv * 512 + lane * 8;       // first of 8 owned cols
    const size_t imgBase = (size_t)img * ((size_t)IMG_H * IMG_W);
    const float NEG = -INFINITY;

    const bool fixL = (wv == 0) && (lane == 0);
    const bool fixR = (wv == 3) && (lane == 63);
    const int offL = fixL ? 0 : -16;          // clamped: stay in-row
    const int offR = fixR ? 16 : 32;

    const int rstart = (r0 - 2) < 0 ? 0 : (r0 - 2);
    const char* pB = (const char*)(scores + imgBase + (size_t)rstart * IMG_W + cl);
    int xn = r0 - 1;                          // row-replication counter (r4-verified)

    float4 Ha0, Ha1, Ha2, Ha3, Ha4, Hb0, Hb1, Hb2, Hb3, Hb4;
    float4 mA0, mB0, mA1, mB1, mA2, mB2;

    unsigned cnt = 0;
    const unsigned wIdx0 =
        (unsigned)(img * IMG_H + r0) * 64u + (unsigned)wv * 16u + (unsigned)(lane >> 2);

    // 20 steps: step u loads row r0-2+u (clamped), H->slot u%5, mid->slot u%3;
    // u>=4 outputs row r0-4+u using mid written at step u-2.
    LOADH(Ha0, Hb0, mA0, mB0);                        // u=0
    LOADH(Ha1, Hb1, mA1, mB1);                        // u=1
    LOADH(Ha2, Hb2, mA2, mB2);                        // u=2
    LOADH(Ha3, Hb3, mA0, mB0);                        // u=3
    LOADH(Ha4, Hb4, mA1, mB1);  OUT(mA2, mB2, 0);     // u=4  -> row r0
    LOADH(Ha0, Hb0, mA2, mB2);  OUT(mA0, mB0, 1);     // u=5
    LOADH(Ha1, Hb1, mA0, mB0);  OUT(mA1, mB1, 2);     // u=6
    LOADH(Ha2, Hb2, mA1, mB1);  OUT(mA2, mB2, 3);     // u=7
    LOADH(Ha3, Hb3, mA2, mB2);  OUT(mA0, mB0, 4);     // u=8
    LOADH(Ha4, Hb4, mA0, mB0);  OUT(mA1, mB1, 5);     // u=9
    LOADH(Ha0, Hb0, mA1, mB1);  OUT(mA2, mB2, 6);     // u=10
    LOADH(Ha1, Hb1, mA2, mB2);  OUT(mA0, mB0, 7);     // u=11
    LOADH(Ha2, Hb2, mA0, mB0);  OUT(mA1, mB1, 8);     // u=12
    LOADH(Ha3, Hb3, mA1, mB1);  OUT(mA2, mB2, 9);     // u=13
    LOADH(Ha4, Hb4, mA2, mB2);  OUT(mA0, mB0, 10);    // u=14
    LOADH(Ha0, Hb0, mA0, mB0);  OUT(mA1, mB1, 11);    // u=15
    LOADH(Ha1, Hb1, mA1, mB1);  OUT(mA2, mB2, 12);    // u=16
    LOADH(Ha2, Hb2, mA2, mB2);  OUT(mA0, mB0, 13);    // u=17
    LOADH(Ha3, Hb3, mA0, mB0);  OUT(mA1, mB1, 14);    // u=18
    LOADH(Ha4, Hb4, mA1, mB1);  OUT(mA2, mB2, 15);    // u=19 -> row r0+15

    // per-wave peak count -> bsum2[cb*4 + wv]; cb == global band index
    unsigned s = cnt;
    s += __shfl_xor(s, 1);
    s += __shfl_xor(s, 2);
    s += __shfl_xor(s, 4);
    s += __shfl_xor(s, 8);
    s += __shfl_xor(s, 16);
    s += __shfl_xor(s, 32);
    if (lane == 0) bsum2[(img * 128 + band) * 4 + wv] = s;
}

// ---------------------------------------------------------------------------
// K2: scan. 1024 cbs x 4 wave-slots -> exclusive bases + total.
// ---------------------------------------------------------------------------
__global__ __launch_bounds__(256) void nms_scan(const unsigned* __restrict__ bsum2,
                                                unsigned* __restrict__ base) {
    __shared__ unsigned wtot[4];
    const int t = threadIdx.x;
    const int lane = t & 63, wid = t >> 6;
    const uint4* p = (const uint4*)bsum2 + t * 4;   // 4 cbs x 4 slots
    unsigned c[4];
#pragma unroll
    for (int i = 0; i < 4; ++i) {
        uint4 a = p[i];
        c[i] = a.x + a.y + a.z + a.w;
    }
    unsigned s0 = c[0], s1 = s0 + c[1], s2 = s1 + c[2], ts = s2 + c[3];
    unsigned sc = ts;
#pragma unroll
    for (int d = 1; d < 64; d <<= 1) {
        unsigned o = __shfl_up(sc, d);
        if (lane >= d) sc += o;
    }
    if (lane == 63) wtot[wid] = sc;
    __syncthreads();
    unsigned wpre = 0;
#pragma unroll
    for (int k = 0; k < 4; ++k) wpre += (k < wid) ? wtot[k] : 0u;
    unsigned excl = wpre + sc - ts;
    ((uint4*)base)[t] = make_uint4(excl, excl + s0, excl + s1, excl + s2);
    if (t == 255) base[1024] = wpre + sc;
}

// ---------------------------------------------------------------------------
// K3: ordered compaction (blocks 0..1023) + -1 tail fill (blocks 1024..).
// words layout identical to r4 (global row-major) -> unchanged, verified.
// ---------------------------------------------------------------------------
__global__ __launch_bounds__(256) void nms_compact(const unsigned* __restrict__ words,
                                                   const unsigned* __restrict__ base,
                                                   int* __restrict__ out) {
    const int t = threadIdx.x;
    const int b = blockIdx.x;
    if (b < 1024) {
        __shared__ unsigned wq[4];
        const int lane = t & 63, wid = t >> 6;
        uint4 q = ((const uint4*)(words + b * 1024))[t];
        unsigned wv[4] = {q.x, q.y, q.z, q.w};
        unsigned tsum = __popc(wv[0]) + __popc(wv[1]) + __popc(wv[2]) + __popc(wv[3]);
        unsigned sc = tsum;
#pragma unroll
        for (int d = 1; d < 64; d <<= 1) {
            unsigned o = __shfl_up(sc, d);
            if (lane >= d) sc += o;
        }
        if (lane == 63) wq[wid] = sc;
        __syncthreads();
        unsigned wpre = 0;
#pragma unroll
        for (int k = 0; k < 4; ++k) wpre += (k < wid) ? wq[k] : 0u;
        unsigned off = base[b] + wpre + sc - tsum;

        const unsigned gword0 = (unsigned)b * 1024u + (unsigned)t * 4u;
#pragma unroll
        for (int wi = 0; wi < 4; ++wi) {
            unsigned m = wv[wi];
            unsigned pbase = (gword0 + wi) << 5;
            while (m) {
                int bit = __builtin_ctz(m);
                m &= m - 1;
                unsigned ppix = pbase + (unsigned)bit;
                int hh = (int)((ppix >> 11) & 2047u);
                int ww = (int)(ppix & 2047u);
                if (off < (unsigned)MAX_PEAKS) {
                    out[off] = hh;
                    out[MAX_PEAKS + off] = ww;
                }
                ++off;
            }
        }
    } else {
        unsigned total = base[1024];
        if (total > (unsigned)MAX_PEAKS) total = MAX_PEAKS;
        unsigned tail = (unsigned)MAX_PEAKS - total;
        unsigned fb = (unsigned)(b - 1024);
        unsigned per = (tail + NFILL - 1) / NFILL;
        unsigned s = total + fb * per;
        unsigned e = s + per;
        if (s > (unsigned)MAX_PEAKS) s = MAX_PEAKS;
        if (e > (unsigned)MAX_PEAKS) e = MAX_PEAKS;
        unsigned a = (s + 3u) & ~3u;
        if (a > e) a = e;
        unsigned e4 = e & ~3u;
        if (e4 < a) e4 = a;
        if ((unsigned)t < a - s) {
            out[s + t] = -1;
            out[MAX_PEAKS + s + t] = -1;
        }
        const int4 m4 = make_int4(-1, -1, -1, -1);
        for (unsigned k = a / 4 + t; k < e4 / 4; k += 256) {
            ((int4*)out)[k] = m4;
            ((int4*)(out + MAX_PEAKS))[k] = m4;
        }
        if ((unsigned)t < e - e4) {
            out[e4 + t] = -1;
            out[MAX_PEAKS + e4 + t] = -1;
        }
    }
}

extern "C" void kernel_launch(void* const* d_in, const int* in_sizes, int n_in,
                              void* d_out, int out_size, void* d_ws, size_t ws_size,
                              hipStream_t stream) {
    const float* scores = (const float*)d_in[0];
    int* out = (int*)d_out;
    unsigned* words = (unsigned*)d_ws;            // 1,048,576 words (4 MB)
    unsigned* bsum2 = words + NWORDS;             // 4096 per-(band,wave) sums
    unsigned* base = bsum2 + 4096;                // 1025 (incl. total)

    nms_mask<<<1024, 256, 0, stream>>>(scores, words, bsum2);
    nms_scan<<<1, 256, 0, stream>>>(bsum2, base);
    nms_compact<<<1024 + NFILL, 256, 0, stream>>>(words, base, out);
}